// Round 5
// baseline (4412.487 us; speedup 1.0000x reference)
//
#include <hip/hip_runtime.h>
#include <stdint.h>

#define D 64
#define KTOT 43744            // 64 + 2016 + 41664  (C(64,1)+C(64,2)+C(64,3))
#define NPAIR 2016
#define NOUT 512
#define MROWS 4096
#define BM 128
#define BN 256
#define BK 64
#define NSTEPS ((KTOT + BK - 1) / BK)   // 684 (last step covers k 43712..43775, tail zeroed)

#define ASTR 144              // A-tile row stride bytes (64 bf16 + pad): 2-way banks only
#define BSTR 144              // B-tile row stride bytes

typedef __attribute__((ext_vector_type(8))) short short8;
typedef __attribute__((ext_vector_type(4))) float f32x4;
typedef __attribute__((ext_vector_type(4))) uint32_t u32x4;

__device__ __forceinline__ unsigned short f2bf(float f) {
  uint32_t u = __float_as_uint(f);
  return (unsigned short)((u + 0x7FFFu + ((u >> 16) & 1u)) >> 16);
}
__device__ __forceinline__ uint32_t pack2(float a, float b) {
  return (uint32_t)f2bf(a) | ((uint32_t)f2bf(b) << 16);
}

// unrank k -> (i, j, l); sentinel 64 (x[64]==1.0) for unused factors. k MUST be < KTOT.
__device__ __forceinline__ void unrank(int k, int& i, int& j, int& l) {
  if (k < D) {
    i = k; j = D; l = D;
  } else if (k < D + NPAIR) {
    int p = k - D;
    i = 0;
    while (p >= D - 1 - i) { p -= D - 1 - i; ++i; }
    j = i + 1 + p; l = D;
  } else {
    int t = k - (D + NPAIR);
    i = 0;
    for (;;) { int c = (D - 1 - i) * (D - 2 - i) / 2; if (t < c) break; t -= c; ++i; }
    j = i + 1;
    while (t >= D - 1 - j) { t -= D - 1 - j; ++j; }
    l = j + 1 + t;
  }
}

// advance to next combo; returns true iff (i,j) changed (pair product refresh needed)
__device__ __forceinline__ bool inc_idx(int& i, int& j, int& l) {
  if (l >= D) {                 // single or pair
    if (j >= D) {               // single
      ++i; if (i == D) { i = 0; j = 1; }          // -> first pair (0,1)
      return true;
    }
    ++j;                        // pair
    if (j == D) { ++i; j = i + 1; if (j == D) { i = 0; j = 1; l = 2; } }
    return true;
  }
  ++l;                          // triple
  if (l == D) {
    ++j; l = j + 1;
    if (l == D) { ++i; j = i + 1; l = j + 1; }   // past-the-end walks are harmless (tail zeroed)
    return true;
  }
  return false;
}

// ---------------- fused feature-gen + bf16 MFMA GEMM (no workspace) ----------------
// grid = (MROWS/BM) * (NOUT/BN) = 64 blocks, 512 threads (8 waves, 2x4 of 64x64 tiles).
// h (pre-LN, +bias) is written to hout = d_out; ln_k then normalizes in place.
__global__ void gemm_fused(const float* __restrict__ x, const float* __restrict__ W,
                           const float* __restrict__ bias, float* __restrict__ hout) {
  __shared__ float Xm[BM * 65];                    // x rows, stride 65 (odd), col 64 = 1.0
  __shared__ __align__(16) char Al[BM * ASTR];     // feats bf16 [128][64] (+pad)
  __shared__ __align__(16) char Bl[BN * BSTR];     // W tile  bf16 [256][64] (+pad)

  const int t = threadIdx.x;
  const int lane = t & 63;
  const int w = t >> 6;               // wave 0..7

  const int mb = blockIdx.x >> 1;     // 0..31
  const int nb = blockIdx.x & 1;      // 0..1

  // ---- x block rows -> LDS ----
  {
    int m = t >> 2, i0 = (t & 3) * 16;
    const float* src = x + (size_t)(mb * BM + m) * D + i0;
    #pragma unroll
    for (int c = 0; c < 4; ++c) {
      f32x4 v = *(const f32x4*)(src + c * 4);
      #pragma unroll
      for (int e = 0; e < 4; ++e) Xm[m * 65 + i0 + c * 4 + e] = v[e];
    }
    if ((t & 3) == 0) Xm[m * 65 + D] = 1.0f;
  }
  __syncthreads();

  f32x4 acc[4][4];
  #pragma unroll
  for (int a = 0; a < 4; ++a)
    #pragma unroll
    for (int b = 0; b < 4; ++b) {
      f32x4 z = {0.f, 0.f, 0.f, 0.f};
      acc[a][b] = z;
    }

  const int wr = w >> 2, wc = w & 3;  // wave tile (64x64) coords: 2 x 4

  // fragment read base offsets (bytes); per kc add kc*64
  int Abase[4], Bbase[4];
  const int g = lane >> 4;            // k-group 0..3 (8 bf16 each)
  #pragma unroll
  for (int fm = 0; fm < 4; ++fm) {
    int m = wr * 64 + fm * 16 + (lane & 15);
    Abase[fm] = m * ASTR + g * 16;
  }
  #pragma unroll
  for (int fn = 0; fn < 4; ++fn) {
    int n = wc * 64 + fn * 16 + (lane & 15);
    Bbase[fn] = n * BSTR + g * 16;
  }

  // feat-gen mapping: thread -> (row fg_m = t&127, k-chunk fg_kh = t>>7 in [0,4)), 16 k each
  const int fg_m = t & 127;
  const int fg_kh = t >> 7;
  const float* xr = &Xm[fg_m * 65];
  const uint32_t Awr = (uint32_t)(fg_m * ASTR + fg_kh * 32);

  for (int ks = 0; ks < NSTEPS; ++ks) {
    const int k0 = ks * BK;

    // ---- stage B: W fp32 -> bf16 LDS (register-staged, coalesced across lanes) ----
    #pragma unroll
    for (int i2 = 0; i2 < 4; ++i2) {
      int sid = t + i2 * 512;          // 0..2047 = 256 n x 8 k-slots
      int n = sid & 255, s = sid >> 8;
      const float* wp = W + (size_t)(k0 + s * 8) * NOUT + nb * BN + n;
      float f[8];
      #pragma unroll
      for (int e = 0; e < 8; ++e)
        f[e] = (k0 + s * 8 + e < KTOT) ? wp[(size_t)e * NOUT] : 0.0f;
      u32x4 v = {pack2(f[0], f[1]), pack2(f[2], f[3]),
                 pack2(f[4], f[5]), pack2(f[6], f[7])};
      *(u32x4*)(Bl + n * BSTR + s * 16) = v;
    }

    // ---- generate A feats (16 per thread, run-shared pair product; tail zeroed) ----
    {
      const int kbase = k0 + fg_kh * 16;
      int ii, jj, ll;
      unrank(kbase < KTOT ? kbase : KTOT - 1, ii, jj, ll);
      float pprod = xr[ii] * xr[jj];
      float fv[16];
      #pragma unroll
      for (int h = 0; h < 16; ++h) {
        fv[h] = (kbase + h < KTOT) ? pprod * xr[ll] : 0.0f;
        if (h < 15) {
          if (inc_idx(ii, jj, ll)) pprod = xr[ii] * xr[jj];
        }
      }
      u32x4 v0 = {pack2(fv[0], fv[1]), pack2(fv[2], fv[3]),
                  pack2(fv[4], fv[5]), pack2(fv[6], fv[7])};
      u32x4 v1 = {pack2(fv[8], fv[9]), pack2(fv[10], fv[11]),
                  pack2(fv[12], fv[13]), pack2(fv[14], fv[15])};
      *(u32x4*)(Al + Awr) = v0;
      *(u32x4*)(Al + Awr + 16) = v1;
    }

    __syncthreads();

    // ---- MFMA ----
    #pragma unroll
    for (int kc = 0; kc < 2; ++kc) {
      short8 av[4], bv[4];
      #pragma unroll
      for (int fm = 0; fm < 4; ++fm)
        av[fm] = *(const short8*)(Al + Abase[fm] + kc * 64);
      #pragma unroll
      for (int fn = 0; fn < 4; ++fn)
        bv[fn] = *(const short8*)(Bl + Bbase[fn] + kc * 64);
      #pragma unroll
      for (int fm = 0; fm < 4; ++fm)
        #pragma unroll
        for (int fn = 0; fn < 4; ++fn)
          acc[fm][fn] = __builtin_amdgcn_mfma_f32_16x16x32_bf16(av[fm], bv[fn], acc[fm][fn], 0, 0, 0);
    }
    __syncthreads();
  }

  // ---- h = acc + bias -> hout. D layout: row=(lane>>4)*4+r, col=lane&15 (m89) ----
  #pragma unroll
  for (int fm = 0; fm < 4; ++fm) {
    int rbase = mb * BM + wr * 64 + fm * 16 + ((lane >> 4) << 2);
    #pragma unroll
    for (int fn = 0; fn < 4; ++fn) {
      int col = nb * BN + wc * 64 + fn * 16 + (lane & 15);
      float bv = bias[col];
      float* dst = hout + (size_t)rbase * NOUT + col;
      #pragma unroll
      for (int r = 0; r < 4; ++r) dst[(size_t)r * NOUT] = acc[fm][fn][r] + bv;
    }
  }
}

// ---------------- LayerNorm + ReLU, in place on d_out ----------------
__global__ void ln_k(float* h, const float* __restrict__ gamma,
                     const float* __restrict__ beta) {
  int row = blockIdx.x;
  int t = threadIdx.x;            // 256 threads, 2 cols each
  float v[2];
  #pragma unroll
  for (int q = 0; q < 2; ++q) v[q] = h[(size_t)row * NOUT + t + q * 256];

  float sum = v[0] + v[1];
  float sq = v[0] * v[0] + v[1] * v[1];
  #pragma unroll
  for (int off = 32; off > 0; off >>= 1) {
    sum += __shfl_xor(sum, off, 64);
    sq  += __shfl_xor(sq, off, 64);
  }
  __shared__ float red[8];
  int wv = t >> 6;
  if ((t & 63) == 0) { red[wv] = sum; red[4 + wv] = sq; }
  __syncthreads();
  sum = red[0] + red[1] + red[2] + red[3];
  sq  = red[4] + red[5] + red[6] + red[7];
  float mu = sum * (1.0f / NOUT);
  float var = sq * (1.0f / NOUT) - mu * mu;
  float rs = rsqrtf(var + 1e-5f);
  #pragma unroll
  for (int q = 0; q < 2; ++q) {
    int c = t + q * 256;
    float hn = (v[q] - mu) * rs * gamma[c] + beta[c];
    h[(size_t)row * NOUT + c] = fmaxf(hn, 0.0f);
  }
}

extern "C" void kernel_launch(void* const* d_in, const int* in_sizes, int n_in,
                              void* d_out, int out_size, void* d_ws, size_t ws_size,
                              hipStream_t stream) {
  const float* x     = (const float*)d_in[0];
  const float* W     = (const float*)d_in[1];
  const float* bias  = (const float*)d_in[2];
  const float* gamma = (const float*)d_in[3];
  const float* beta  = (const float*)d_in[4];
  float* out = (float*)d_out;

  // Workspace deliberately UNUSED this round (bisection discipline).
  (void)d_ws; (void)ws_size; (void)in_sizes; (void)n_in; (void)out_size;

  gemm_fused<<<(MROWS / BM) * (NOUT / BN), 512, 0, stream>>>(x, W, bias, out);
  ln_k<<<MROWS, 256, 0, stream>>>(out, gamma, beta);
}

// Round 6
// 464.143 us; speedup vs baseline: 9.5067x; 9.5067x over previous
//
#include <hip/hip_runtime.h>
#include <stdint.h>

#define D 64
#define KTOT 43744            // C(64,1)+C(64,2)+C(64,3) = 64+2016+41664
#define NPAIR 2016
#define NOUT 512
#define MROWS 4096
#define BM 128
#define BN 128
#define BK 64
#define NSTEPS ((KTOT + BK - 1) / BK)   // 684
#define KPAD (NSTEPS * BK)              // 43776 (tail idx = sentinel, weight 0)

typedef __attribute__((ext_vector_type(8))) short short8;
typedef __attribute__((ext_vector_type(4))) float f32x4;
typedef __attribute__((ext_vector_type(4))) uint32_t u32x4;

__device__ __forceinline__ uint32_t cvtpk(float lo, float hi) {
  uint32_t r;
  asm("v_cvt_pk_bf16_f32 %0, %1, %2" : "=v"(r) : "v"(lo), "v"(hi));
  return r;
}

// unrank k -> (i, j, l); sentinel 64 (x[64]==1.0) for unused factors. k < KTOT.
__device__ __forceinline__ void unrank(int k, int& i, int& j, int& l) {
  if (k < D) {
    i = k; j = D; l = D;
  } else if (k < D + NPAIR) {
    int p = k - D;
    i = 0;
    while (p >= D - 1 - i) { p -= D - 1 - i; ++i; }
    j = i + 1 + p; l = D;
  } else {
    int t = k - (D + NPAIR);
    i = 0;
    for (;;) { int c = (D - 1 - i) * (D - 2 - i) / 2; if (t < c) break; t -= c; ++i; }
    j = i + 1;
    while (t >= D - 1 - j) { t -= D - 1 - j; ++j; }
    l = j + 1 + t;
  }
}

// next combo; true iff (i,j) changed
__device__ __forceinline__ bool inc_idx(int& i, int& j, int& l) {
  if (l >= D) {
    if (j >= D) { ++i; if (i == D) { i = 0; j = 1; } return true; }
    ++j;
    if (j == D) { ++i; j = i + 1; if (j == D) { i = 0; j = 1; l = 2; } }
    return true;
  }
  ++l;
  if (l == D) {
    ++j; l = j + 1;
    if (l == D) { ++i; j = i + 1; l = j + 1; }
    return true;
  }
  return false;
}

// ---------------- kernel 1: idx table, padded to KPAD with sentinel ----------------
__global__ void build_idx_k(uint32_t* __restrict__ idx) {
  int k = blockIdx.x * 256 + threadIdx.x;
  if (k >= KPAD) return;
  if (k >= KTOT) { idx[k] = 64u | (64u << 8) | (64u << 16); return; }
  int i, j, l;
  unrank(k, i, j, l);
  idx[k] = (uint32_t)i | ((uint32_t)j << 8) | ((uint32_t)l << 16);
}

// ---------------- kernel 2: fused feature-gen + bf16 MFMA GEMM, split-K ----------------
// BM=128 x BN=128, BK=64, 512 threads = 8 waves (2x4, wave tile 64x32).
// LDS 66KB -> 2 blocks/CU. XOR swizzle: 16B slot_phys = slot ^ (row&7), 128B rows.
template<int USE_IDX>
__global__ void __launch_bounds__(512, 4)
gemm_k(const float* __restrict__ x, const float* __restrict__ W,
       const uint32_t* __restrict__ idxg, float* __restrict__ part,
       int S, int Slog, int steps_per) {
  __shared__ float Xm[BM * 65];                    // x rows, stride 65 dwords, col 64 = 1.0
  __shared__ __align__(16) char Al[BM * 128];      // feats bf16 [128][64], swizzled
  __shared__ __align__(16) char Bl[BN * 128];      // W tile  bf16 [128][64], swizzled

  const int t = threadIdx.x;
  const int lane = t & 63;
  const int w = t >> 6;               // wave 0..7

  const int mb = blockIdx.x & 31;
  const int ns = blockIdx.x >> 5;     // (nb,sb) group: blocks sharing a W slice are adjacent
  const int nb = ns >> Slog;
  const int sb = ns & (S - 1);

  // ---- x block rows -> LDS ----
  {
    int m = t >> 2, i0 = (t & 3) * 16;
    const float* src = x + (size_t)(mb * BM + m) * D + i0;
    #pragma unroll
    for (int c = 0; c < 4; ++c) {
      f32x4 v = *(const f32x4*)(src + c * 4);
      #pragma unroll
      for (int e = 0; e < 4; ++e) Xm[m * 65 + i0 + c * 4 + e] = v[e];
    }
    if ((t & 3) == 0) Xm[m * 65 + D] = 1.0f;
  }
  __syncthreads();

  f32x4 acc[4][2];
  #pragma unroll
  for (int a = 0; a < 4; ++a)
    #pragma unroll
    for (int b = 0; b < 2; ++b) {
      f32x4 z = {0.f, 0.f, 0.f, 0.f};
      acc[a][b] = z;
    }

  const int wr = w >> 2, wc = w & 3;  // 2x4 wave grid, wave tile 64 rows x 32 cols
  const int g = lane >> 4;            // k-group 0..3

  int Abase[4], Bbase[2];
  #pragma unroll
  for (int fm = 0; fm < 4; ++fm) {
    int m = wr * 64 + fm * 16 + (lane & 15);
    Abase[fm] = m * 128 + ((g ^ (m & 7)) << 4);
  }
  #pragma unroll
  for (int fn = 0; fn < 2; ++fn) {
    int n = wc * 32 + fn * 16 + (lane & 15);
    Bbase[fn] = n * 128 + ((g ^ (n & 7)) << 4);
  }

  // feat-gen mapping: fg_m = t&127 (row), fg_kh = t>>7 (16-k chunk); wave-uniform k
  const int fg_m = t & 127;
  const int fg_kh = t >> 7;
  const float* xr = &Xm[fg_m * 65];
  const uint32_t Awr0 = (uint32_t)(fg_m * 128 + (((fg_kh * 2 + 0) ^ (fg_m & 7)) << 4));
  const uint32_t Awr1 = (uint32_t)(fg_m * 128 + (((fg_kh * 2 + 1) ^ (fg_m & 7)) << 4));

  const int ks0 = sb * steps_per;
  const int ks1 = (ks0 + steps_per < NSTEPS) ? (ks0 + steps_per) : NSTEPS;

  for (int ks = ks0; ks < ks1; ++ks) {
    const int k0 = ks * BK;

    // ---- early global loads (overlap with feat-gen below) ----
    u32x4 I[4];
    if (USE_IDX) {
      const u32x4* ip = (const u32x4*)(idxg + k0 + fg_kh * 16);
      #pragma unroll
      for (int c = 0; c < 4; ++c) I[c] = ip[c];
    }
    float fw[16];
    #pragma unroll
    for (int i2 = 0; i2 < 2; ++i2) {
      int u = t + i2 * 512;            // unit: n = u&127, slot s = u>>7
      int n = u & 127, s = u >> 7;
      const float* wp = W + (size_t)(k0 + s * 8) * NOUT + nb * BN + n;
      #pragma unroll
      for (int e = 0; e < 8; ++e)
        fw[i2 * 8 + e] = (k0 + s * 8 + e < KTOT) ? wp[(size_t)e * NOUT] : 0.0f;
    }

    // ---- generate A feats (16/thread; run-shared pair product, wave-uniform branch) ----
    {
      uint32_t pk[8];
      if (USE_IDX) {
        uint32_t prev = 0xFFFFFFFFu;
        float pp = 0.0f;
        #pragma unroll
        for (int c = 0; c < 4; ++c) {
          float fv[4];
          #pragma unroll
          for (int e = 0; e < 4; ++e) {
            uint32_t uu = I[c][e];
            uint32_t ij = uu & 0xFFFFu;
            if (ij != prev) { pp = xr[uu & 0xFFu] * xr[(uu >> 8) & 0xFFu]; prev = ij; }
            fv[e] = pp * xr[uu >> 16];
          }
          pk[c * 2 + 0] = cvtpk(fv[0], fv[1]);
          pk[c * 2 + 1] = cvtpk(fv[2], fv[3]);
        }
      } else {
        const int kbase = k0 + fg_kh * 16;
        int ii, jj, ll;
        unrank(kbase < KTOT ? kbase : KTOT - 1, ii, jj, ll);
        float pp = xr[ii] * xr[jj];
        float fv[16];
        #pragma unroll
        for (int h = 0; h < 16; ++h) {
          fv[h] = (kbase + h < KTOT) ? pp * xr[ll] : 0.0f;
          if (h < 15) {
            if (inc_idx(ii, jj, ll)) pp = xr[ii] * xr[jj];
          }
        }
        #pragma unroll
        for (int c = 0; c < 8; ++c) pk[c] = cvtpk(fv[2 * c], fv[2 * c + 1]);
      }
      u32x4 v0 = {pk[0], pk[1], pk[2], pk[3]};
      u32x4 v1 = {pk[4], pk[5], pk[6], pk[7]};
      *(u32x4*)(Al + Awr0) = v0;
      *(u32x4*)(Al + Awr1) = v1;
    }

    // ---- pack + write B tile ----
    #pragma unroll
    for (int i2 = 0; i2 < 2; ++i2) {
      int u = t + i2 * 512;
      int n = u & 127, s = u >> 7;
      u32x4 v = {cvtpk(fw[i2 * 8 + 0], fw[i2 * 8 + 1]),
                 cvtpk(fw[i2 * 8 + 2], fw[i2 * 8 + 3]),
                 cvtpk(fw[i2 * 8 + 4], fw[i2 * 8 + 5]),
                 cvtpk(fw[i2 * 8 + 6], fw[i2 * 8 + 7])};
      *(u32x4*)(Bl + n * 128 + ((s ^ (n & 7)) << 4)) = v;
    }

    __syncthreads();

    // ---- MFMA: slot(kc=1) = slot(kc=0) ^ 4  ->  addr ^ 0x40 ----
    #pragma unroll
    for (int kc = 0; kc < 2; ++kc) {
      short8 av[4], bv[2];
      #pragma unroll
      for (int fm = 0; fm < 4; ++fm)
        av[fm] = *(const short8*)(Al + (Abase[fm] ^ (kc << 6)));
      #pragma unroll
      for (int fn = 0; fn < 2; ++fn)
        bv[fn] = *(const short8*)(Bl + (Bbase[fn] ^ (kc << 6)));
      #pragma unroll
      for (int fm = 0; fm < 4; ++fm)
        #pragma unroll
        for (int fn = 0; fn < 2; ++fn)
          acc[fm][fn] = __builtin_amdgcn_mfma_f32_16x16x32_bf16(av[fm], bv[fn], acc[fm][fn], 0, 0, 0);
    }
    __syncthreads();
  }

  // ---- store partials. D layout: row=(lane>>4)*4+r, col=lane&15 (m89-verified) ----
  #pragma unroll
  for (int fm = 0; fm < 4; ++fm) {
    int rbase = mb * BM + wr * 64 + fm * 16 + ((lane >> 4) << 2);
    #pragma unroll
    for (int fn = 0; fn < 2; ++fn) {
      int col = nb * BN + wc * 32 + fn * 16 + (lane & 15);
      float* dst = part + ((size_t)sb * MROWS + rbase) * NOUT + col;
      #pragma unroll
      for (int r = 0; r < 4; ++r) dst[(size_t)r * NOUT] = acc[fm][fn][r];
    }
  }
}

// ---------------- kernel 3: sum partials + bias + LayerNorm + ReLU ----------------
// no __restrict__ on part/out: they alias when S==1.
__global__ void ln_k(const float* part, int S,
                     const float* __restrict__ bias, const float* __restrict__ gamma,
                     const float* __restrict__ beta, float* out) {
  int row = blockIdx.x;
  int t = threadIdx.x;            // 256 threads, 2 cols each
  float v[2];
  #pragma unroll
  for (int q = 0; q < 2; ++q) {
    int c = t + q * 256;
    float s = bias[c];
    for (int sbi = 0; sbi < S; ++sbi)
      s += part[((size_t)sbi * MROWS + row) * NOUT + c];
    v[q] = s;
  }
  float sum = v[0] + v[1];
  float sq = v[0] * v[0] + v[1] * v[1];
  #pragma unroll
  for (int off = 32; off > 0; off >>= 1) {
    sum += __shfl_xor(sum, off, 64);
    sq  += __shfl_xor(sq, off, 64);
  }
  __shared__ float red[8];
  int wv = t >> 6;
  if ((t & 63) == 0) { red[wv] = sum; red[4 + wv] = sq; }
  __syncthreads();
  sum = red[0] + red[1] + red[2] + red[3];
  sq  = red[4] + red[5] + red[6] + red[7];
  float mu = sum * (1.0f / NOUT);
  float var = sq * (1.0f / NOUT) - mu * mu;
  float rs = rsqrtf(var + 1e-5f);
  #pragma unroll
  for (int q = 0; q < 2; ++q) {
    int c = t + q * 256;
    float hn = (v[q] - mu) * rs * gamma[c] + beta[c];
    out[(size_t)row * NOUT + c] = fmaxf(hn, 0.0f);
  }
}

extern "C" void kernel_launch(void* const* d_in, const int* in_sizes, int n_in,
                              void* d_out, int out_size, void* d_ws, size_t ws_size,
                              hipStream_t stream) {
  const float* x     = (const float*)d_in[0];
  const float* W     = (const float*)d_in[1];
  const float* bias  = (const float*)d_in[2];
  const float* gamma = (const float*)d_in[3];
  const float* beta  = (const float*)d_in[4];
  float* out = (float*)d_out;
  (void)in_sizes; (void)n_in; (void)out_size;

  const size_t IDXB = 262144;   // >= KPAD*4 = 175104, 16B-aligned region
  const size_t ONEPART = (size_t)MROWS * NOUT * sizeof(float);  // 8 MB

  char* base = (char*)d_ws;
  const bool has_idx = ws_size >= IDXB;
  uint32_t* idx = (uint32_t*)base;

  // pick largest split S in {8,4,2} whose partial buffer fits after idx; else S=1.
  int S = 1, Slog = 0;
  float* part = out;              // S==1: h accumulates straight into d_out
  if (has_idx) {
    for (int cand = 8; cand >= 2; cand >>= 1) {
      if (ws_size >= IDXB + (size_t)cand * ONEPART) {
        S = cand;
        Slog = (cand == 8) ? 3 : (cand == 4) ? 2 : 1;
        part = (float*)(base + IDXB);
        break;
      }
    }
  }
  int steps_per = (NSTEPS + S - 1) / S;
  int grid = 32 * (NOUT / BN) * S;     // mb x nb x sb

  if (has_idx) {
    build_idx_k<<<KPAD / 256, 256, 0, stream>>>(idx);
    gemm_k<1><<<grid, 512, 0, stream>>>(x, W, idx, part, S, Slog, steps_per);
  } else {
    gemm_k<0><<<grid, 512, 0, stream>>>(x, W, nullptr, part, S, Slog, steps_per);
  }
  ln_k<<<MROWS, 256, 0, stream>>>(part, S, bias, gamma, beta, out);
}

// Round 7
// 271.829 us; speedup vs baseline: 16.2326x; 1.7075x over previous
//
#include <hip/hip_runtime.h>
#include <stdint.h>

#define D 64
#define KTOT 43744            // C(64,1)+C(64,2)+C(64,3)
#define NPAIR 2016
#define NOUT 512
#define MROWS 4096
#define BM 128
#define BN 256
#define BK 64
#define NSTEPS ((KTOT + BK - 1) / BK)   // 684
#define KPAD (NSTEPS * BK)              // 43776
#define K2B (KPAD * 2)                  // Wt row bytes = 87552

typedef __attribute__((ext_vector_type(8))) short short8;
typedef __attribute__((ext_vector_type(4))) float f32x4;
typedef __attribute__((ext_vector_type(4))) uint32_t u32x4;

__device__ __forceinline__ uint32_t cvtpk(float lo, float hi) {
  uint32_t r;
  asm("v_cvt_pk_bf16_f32 %0, %1, %2" : "=v"(r) : "v"(lo), "v"(hi));
  return r;
}

__device__ __forceinline__ void load_b128_to_lds(const void* gsrc, void* ldst) {
  typedef const __attribute__((address_space(1))) uint32_t* GP;
  typedef __attribute__((address_space(3))) uint32_t* LP;
  __builtin_amdgcn_global_load_lds((GP)(uintptr_t)gsrc, (LP)(uintptr_t)ldst, 16, 0, 0);
}

// unrank k -> (i,j,l); sentinel 64 for unused factors. k < KTOT.
__device__ __forceinline__ void unrank(int k, int& i, int& j, int& l) {
  if (k < D) {
    i = k; j = D; l = D;
  } else if (k < D + NPAIR) {
    int p = k - D;
    i = 0;
    while (p >= D - 1 - i) { p -= D - 1 - i; ++i; }
    j = i + 1 + p; l = D;
  } else {
    int t = k - (D + NPAIR);
    i = 0;
    for (;;) { int c = (D - 1 - i) * (D - 2 - i) / 2; if (t < c) break; t -= c; ++i; }
    j = i + 1;
    while (t >= D - 1 - j) { t -= D - 1 - j; ++j; }
    l = j + 1 + t;
  }
}

__device__ __forceinline__ bool inc_idx(int& i, int& j, int& l) {
  if (l >= D) {
    if (j >= D) { ++i; if (i == D) { i = 0; j = 1; } return true; }
    ++j;
    if (j == D) { ++i; j = i + 1; if (j == D) { i = 0; j = 1; l = 2; } }
    return true;
  }
  ++l;
  if (l == D) {
    ++j; l = j + 1;
    if (l == D) { ++i; j = i + 1; l = j + 1; }
    return true;
  }
  return false;
}

// ---------------- kernel 1: idx table, padded to KPAD with sentinel ----------------
__global__ void build_idx_k(uint32_t* __restrict__ idx) {
  int k = blockIdx.x * 256 + threadIdx.x;
  if (k >= KPAD) return;
  if (k >= KTOT) { idx[k] = 64u | (64u << 8) | (64u << 16); return; }
  int i, j, l;
  unrank(k, i, j, l);
  idx[k] = (uint32_t)i | ((uint32_t)j << 8) | ((uint32_t)l << 16);
}

// ---------------- kernel 2: W [KTOT][512] fp32 -> Wt [512][KPAD] bf16 ----------------
// 16B slot s of each 64-k chunk stored at phys slot s ^ (n&7); k >= KTOT zeroed.
__global__ void wtrans_k(const float* __restrict__ W, char* __restrict__ Wt) {
  __shared__ float tile[64][65];
  int bk = blockIdx.x;          // k tile (0..NSTEPS-1)
  int bn = blockIdx.y;          // n tile (0..7)
  int t = threadIdx.x;          // 256
  int k0 = bk * 64, n0 = bn * 64;
  int col = t & 63, r0 = t >> 6;
  #pragma unroll
  for (int p = 0; p < 16; ++p) {
    int row = p * 4 + r0;
    tile[col][row] = (k0 + row < KTOT) ? W[(size_t)(k0 + row) * NOUT + (n0 + col)] : 0.0f;
  }
  __syncthreads();
  for (int u = t; u < 512; u += 256) {
    int n = u >> 3, s = u & 7;
    int ng = n0 + n;
    u32x4 v = {cvtpk(tile[n][s * 8 + 0], tile[n][s * 8 + 1]),
               cvtpk(tile[n][s * 8 + 2], tile[n][s * 8 + 3]),
               cvtpk(tile[n][s * 8 + 4], tile[n][s * 8 + 5]),
               cvtpk(tile[n][s * 8 + 6], tile[n][s * 8 + 7])};
    int sp = s ^ (ng & 7);
    *(u32x4*)(Wt + (size_t)ng * K2B + (size_t)k0 * 2 + (sp << 4)) = v;
  }
}

// ---------------- kernel 3: fused feature-gen + bf16 MFMA GEMM, split-K ----------------
// BM=128 x BN=256, BK=64, 8 waves (2x4 grid of 64x64 wave tiles), 2 blocks/CU (80KB LDS).
template<int USE_WT, int USE_IDX>
__global__ void __launch_bounds__(512, 4)
gemm_k(const float* __restrict__ x, const float* __restrict__ W,
       const char* __restrict__ Wt, const uint32_t* __restrict__ idxg,
       float* __restrict__ part, int S, int Slog, int steps_per) {
  __shared__ float XmT[D * 128];                   // 32KB, [i][m] transposed x tile
  __shared__ __align__(16) char Al[BM * 128];      // 16KB feats bf16, slot ^= row&7
  __shared__ __align__(16) char Bl[BN * 128];      // 32KB W tile, swizzle baked (Wt) or applied

  const int t = threadIdx.x;
  const int lane = t & 63;
  const int w = t >> 6;               // wave 0..7

  const int mb = blockIdx.x & 31;
  const int ns = blockIdx.x >> 5;
  const int nb = ns >> Slog;          // 0..1
  const int sb = ns & (S - 1);

  // ---- x block rows -> LDS transposed: XmT[i*128 + m] ----
  {
    int m = t >> 2, i0 = (t & 3) * 16;
    const float* src = x + (size_t)(mb * BM + m) * D + i0;
    #pragma unroll
    for (int c = 0; c < 4; ++c) {
      f32x4 v = *(const f32x4*)(src + c * 4);
      #pragma unroll
      for (int e = 0; e < 4; ++e) XmT[(i0 + c * 4 + e) * 128 + m] = v[e];
    }
  }
  __syncthreads();

  f32x4 acc[4][4];
  #pragma unroll
  for (int a = 0; a < 4; ++a)
    #pragma unroll
    for (int b = 0; b < 4; ++b) {
      f32x4 z = {0.f, 0.f, 0.f, 0.f};
      acc[a][b] = z;
    }

  const int wr = w >> 2, wc = w & 3;  // 2x4 wave grid, wave tile 64x64
  const int g = lane >> 4;            // k-group 0..3

  int Abase[4], Bbase[4];
  #pragma unroll
  for (int fm = 0; fm < 4; ++fm) {
    int m = wr * 64 + fm * 16 + (lane & 15);
    Abase[fm] = m * 128 + ((g ^ (m & 7)) << 4);
  }
  #pragma unroll
  for (int fn = 0; fn < 4; ++fn) {
    int n = wc * 64 + fn * 16 + (lane & 15);
    Bbase[fn] = n * 128 + ((g ^ (n & 7)) << 4);
  }

  // B staging bases (Wt path): wave w covers rows [w*32,(w+1)*32), 4 x 1KB gload_lds
  uint32_t BrowOff[4];
  #pragma unroll
  for (int inst = 0; inst < 4; ++inst) {
    int row = nb * BN + w * 32 + inst * 8 + (lane >> 3);
    BrowOff[inst] = (uint32_t)row * K2B + ((lane & 7) << 4);
  }

  // feat-gen: fg_m = t&127 (row), fg_kh = t>>7 (16-k chunk); k-window wave-uniform
  const int fg_m = t & 127;
  const int fg_kh = t >> 7;
  const float* xcol = XmT + fg_m;     // XT(i) = xcol[i*128]
  const uint32_t Awr0 = (uint32_t)(fg_m * 128 + (((fg_kh * 2 + 0) ^ (fg_m & 7)) << 4));
  const uint32_t Awr1 = (uint32_t)(fg_m * 128 + (((fg_kh * 2 + 1) ^ (fg_m & 7)) << 4));

  const int ks0 = sb * steps_per;
  const int ks1 = (ks0 + steps_per < NSTEPS) ? (ks0 + steps_per) : NSTEPS;

  for (int ks = ks0; ks < ks1; ++ks) {
    const int k0 = ks * BK;

    // ---- stage B: issue first so it flies under feat-gen ----
    if (USE_WT) {
      #pragma unroll
      for (int inst = 0; inst < 4; ++inst)
        load_b128_to_lds(Wt + BrowOff[inst] + (uint32_t)k0 * 2,
                         Bl + w * 4096 + inst * 1024);
    }

    // ---- generate A feats (16/thread) ----
    {
      uint32_t pk[8];
      const int kbase = k0 + fg_kh * 16;
      if (USE_IDX) {
        u32x4 I[4];
        const u32x4* ip = (const u32x4*)(idxg + kbase);
        #pragma unroll
        for (int c = 0; c < 4; ++c) I[c] = ip[c];

        if (kbase >= D + NPAIR) {
          // pure triples (95% of steps): run-shared pair product, no sentinel checks
          uint32_t prev = 0xFFFFFFFFu;
          float pp = 0.0f;
          #pragma unroll
          for (int c = 0; c < 4; ++c) {
            float fv[4];
            #pragma unroll
            for (int e = 0; e < 4; ++e) {
              uint32_t uu = I[c][e];
              uint32_t ij = uu & 0xFFFFu;
              if (ij != prev) {          // wave-uniform branch (idx lane-invariant)
                pp = xcol[(uu & 63u) * 128] * xcol[((uu >> 8) & 63u) * 128];
                prev = ij;
              }
              fv[e] = pp * xcol[((uu >> 16) & 63u) * 128];
            }
            pk[c * 2 + 0] = cvtpk(fv[0], fv[1]);
            pk[c * 2 + 1] = cvtpk(fv[2], fv[3]);
          }
        } else {
          // singles/pairs region (33 steps, sb==0 only): sentinel-guarded
          #pragma unroll
          for (int c = 0; c < 4; ++c) {
            float fv[4];
            #pragma unroll
            for (int e = 0; e < 4; ++e) {
              uint32_t uu = I[c][e];
              uint32_t ji = (uu >> 8) & 0xFFu, li = uu >> 16;
              float xi = xcol[(uu & 63u) * 128];
              float xj = (ji < 64u) ? xcol[(ji & 63u) * 128] : 1.0f;
              float xl = (li < 64u) ? xcol[(li & 63u) * 128] : 1.0f;
              fv[e] = xi * xj * xl;
            }
            pk[c * 2 + 0] = cvtpk(fv[0], fv[1]);
            pk[c * 2 + 1] = cvtpk(fv[2], fv[3]);
          }
        }
      } else {
        int ii, jj, ll;
        unrank(kbase < KTOT ? kbase : KTOT - 1, ii, jj, ll);
        float fv[16];
        #pragma unroll
        for (int h = 0; h < 16; ++h) {
          float xi = xcol[(ii & 63) * 128];
          float xj = (jj < 64) ? xcol[(jj & 63) * 128] : 1.0f;
          float xl = (ll < 64) ? xcol[(ll & 63) * 128] : 1.0f;
          fv[h] = (kbase + h < KTOT) ? xi * xj * xl : 0.0f;
          if (h < 15) inc_idx(ii, jj, ll);
        }
        #pragma unroll
        for (int c = 0; c < 8; ++c) pk[c] = cvtpk(fv[2 * c], fv[2 * c + 1]);
      }
      u32x4 v0 = {pk[0], pk[1], pk[2], pk[3]};
      u32x4 v1 = {pk[4], pk[5], pk[6], pk[7]};
      *(u32x4*)(Al + Awr0) = v0;
      *(u32x4*)(Al + Awr1) = v1;
    }

    // ---- direct-W staging fallback (no Wt in ws) ----
    if (!USE_WT) {
      #pragma unroll
      for (int i2 = 0; i2 < 4; ++i2) {
        int u = t + i2 * 512;            // 2048 units: n = u&255, slot s = u>>8
        int n = u & 255, s = u >> 8;
        const float* wp = W + (size_t)(k0 + s * 8) * NOUT + nb * BN + n;
        float f[8];
        #pragma unroll
        for (int e = 0; e < 8; ++e)
          f[e] = (k0 + s * 8 + e < KTOT) ? wp[(size_t)e * NOUT] : 0.0f;
        u32x4 v = {cvtpk(f[0], f[1]), cvtpk(f[2], f[3]),
                   cvtpk(f[4], f[5]), cvtpk(f[6], f[7])};
        *(u32x4*)(Bl + n * 128 + ((s ^ (n & 7)) << 4)) = v;
      }
    }

    __syncthreads();   // drains vmcnt (gload_lds) + lgkm (A/B writes)

    // ---- MFMA: phys slot(kc=1) = slot(kc=0) ^ 4 -> addr ^ 0x40 ----
    #pragma unroll
    for (int kc = 0; kc < 2; ++kc) {
      short8 av[4], bv[4];
      #pragma unroll
      for (int fm = 0; fm < 4; ++fm)
        av[fm] = *(const short8*)(Al + (Abase[fm] ^ (kc << 6)));
      #pragma unroll
      for (int fn = 0; fn < 4; ++fn)
        bv[fn] = *(const short8*)(Bl + (Bbase[fn] ^ (kc << 6)));
      #pragma unroll
      for (int fm = 0; fm < 4; ++fm)
        #pragma unroll
        for (int fn = 0; fn < 4; ++fn)
          acc[fm][fn] = __builtin_amdgcn_mfma_f32_16x16x32_bf16(av[fm], bv[fn], acc[fm][fn], 0, 0, 0);
    }
    __syncthreads();
  }

  // ---- store partials. D layout: row=(lane>>4)*4+r, col=lane&15 (m89-verified) ----
  #pragma unroll
  for (int fm = 0; fm < 4; ++fm) {
    int rbase = mb * BM + wr * 64 + fm * 16 + ((lane >> 4) << 2);
    #pragma unroll
    for (int fn = 0; fn < 4; ++fn) {
      int col = nb * BN + wc * 64 + fn * 16 + (lane & 15);
      float* dst = part + ((size_t)sb * MROWS + rbase) * NOUT + col;
      #pragma unroll
      for (int r = 0; r < 4; ++r) dst[(size_t)r * NOUT] = acc[fm][fn][r];
    }
  }
}

// ---------------- kernel 4: sum partials + bias + LayerNorm + ReLU ----------------
// no __restrict__ on part/out: alias when S==1.
__global__ void ln_k(const float* part, int S,
                     const float* __restrict__ bias, const float* __restrict__ gamma,
                     const float* __restrict__ beta, float* out) {
  int row = blockIdx.x;
  int t = threadIdx.x;            // 256 threads, 2 cols each
  float v[2];
  #pragma unroll
  for (int q = 0; q < 2; ++q) {
    int c = t + q * 256;
    float s = bias[c];
    for (int sbi = 0; sbi < S; ++sbi)
      s += part[((size_t)sbi * MROWS + row) * NOUT + c];
    v[q] = s;
  }
  float sum = v[0] + v[1];
  float sq = v[0] * v[0] + v[1] * v[1];
  #pragma unroll
  for (int off = 32; off > 0; off >>= 1) {
    sum += __shfl_xor(sum, off, 64);
    sq  += __shfl_xor(sq, off, 64);
  }
  __shared__ float red[8];
  int wv = t >> 6;
  if ((t & 63) == 0) { red[wv] = sum; red[4 + wv] = sq; }
  __syncthreads();
  sum = red[0] + red[1] + red[2] + red[3];
  sq  = red[4] + red[5] + red[6] + red[7];
  float mu = sum * (1.0f / NOUT);
  float var = sq * (1.0f / NOUT) - mu * mu;
  float rs = rsqrtf(var + 1e-5f);
  #pragma unroll
  for (int q = 0; q < 2; ++q) {
    int c = t + q * 256;
    float hn = (v[q] - mu) * rs * gamma[c] + beta[c];
    out[(size_t)row * NOUT + c] = fmaxf(hn, 0.0f);
  }
}

extern "C" void kernel_launch(void* const* d_in, const int* in_sizes, int n_in,
                              void* d_out, int out_size, void* d_ws, size_t ws_size,
                              hipStream_t stream) {
  const float* x     = (const float*)d_in[0];
  const float* W     = (const float*)d_in[1];
  const float* bias  = (const float*)d_in[2];
  const float* gamma = (const float*)d_in[3];
  const float* beta  = (const float*)d_in[4];
  float* out = (float*)d_out;
  (void)in_sizes; (void)n_in; (void)out_size;

  const size_t IDXB = 262144;                        // >= KPAD*4, keeps alignment
  const size_t WTB  = (size_t)NOUT * K2B;            // 44,826,624
  const size_t PART = (size_t)MROWS * NOUT * sizeof(float);  // 8 MB

  char* base = (char*)d_ws;
  uint32_t* idx = (uint32_t*)base;
  char* Wt = base + IDXB;

  const bool has_idx = ws_size >= IDXB;
  bool use_wt = false;
  int S = 1, Slog = 0;
  // prefer max split-K with Wt; then max split-K without; then S=1 variants
  if (ws_size >= IDXB + WTB + 8 * PART)      { use_wt = true;  S = 8; Slog = 3; }
  else if (ws_size >= IDXB + 8 * PART)       { use_wt = false; S = 8; Slog = 3; }
  else if (ws_size >= IDXB + WTB + 4 * PART) { use_wt = true;  S = 4; Slog = 2; }
  else if (ws_size >= IDXB + 4 * PART)       { use_wt = false; S = 4; Slog = 2; }
  else if (ws_size >= IDXB + WTB + 2 * PART) { use_wt = true;  S = 2; Slog = 1; }
  else if (ws_size >= IDXB + 2 * PART)       { use_wt = false; S = 2; Slog = 1; }
  else if (ws_size >= IDXB + WTB)            { use_wt = true;  S = 1; Slog = 0; }

  float* part = out;   // S==1: h accumulates straight into d_out (ln in place)
  if (S > 1) part = (float*)(base + IDXB + (use_wt ? WTB : 0));

  int steps_per = (NSTEPS + S - 1) / S;
  int grid = 32 * (NOUT / BN) * S;

  if (has_idx) build_idx_k<<<KPAD / 256, 256, 0, stream>>>(idx);
  if (use_wt)  wtrans_k<<<dim3(NSTEPS, 8), 256, 0, stream>>>(W, Wt);

  if (use_wt)
    gemm_k<1, 1><<<grid, 512, 0, stream>>>(x, W, Wt, idx, part, S, Slog, steps_per);
  else if (has_idx)
    gemm_k<0, 1><<<grid, 512, 0, stream>>>(x, W, Wt, idx, part, S, Slog, steps_per);
  else
    gemm_k<0, 0><<<grid, 512, 0, stream>>>(x, W, Wt, nullptr, part, S, Slog, steps_per);

  ln_k<<<MROWS, 256, 0, stream>>>(part, S, bias, gamma, beta, out);
}